// Round 1
// baseline (857.045 us; speedup 1.0000x reference)
//
#include <hip/hip_runtime.h>

// ---------------- graph prep kernels ----------------

__global__ void deg_count_k(const int* __restrict__ dst, int ne, int* __restrict__ deg) {
    int i = blockIdx.x * blockDim.x + threadIdx.x;
    if (i < ne) atomicAdd(&deg[dst[i]], 1);
}

__global__ void dinv_k(const int* __restrict__ deg, float* __restrict__ dinv, int nn) {
    int i = blockIdx.x * blockDim.x + threadIdx.x;
    if (i < nn) dinv[i] = rsqrtf((float)(deg[i] + 1));  // +1 self-loop; always > 0
}

// exclusive scan, hierarchical: scan1 (per-block) -> scan2 (block sums) -> scan3 (add offsets)
__global__ __launch_bounds__(1024) void scan1_k(const int* __restrict__ deg, int* __restrict__ exc,
                                                int* __restrict__ bsum, int nn) {
    __shared__ int sh[1024];
    int tid = threadIdx.x;
    int i = blockIdx.x * 1024 + tid;
    int v = (i < nn) ? deg[i] : 0;
    sh[tid] = v;
    __syncthreads();
    for (int d = 1; d < 1024; d <<= 1) {
        int t = (tid >= d) ? sh[tid - d] : 0;
        __syncthreads();
        sh[tid] += t;
        __syncthreads();
    }
    if (i < nn) exc[i] = sh[tid] - v;           // exclusive within block
    if (tid == 1023) bsum[blockIdx.x] = sh[1023];
}

__global__ __launch_bounds__(1024) void scan2_k(int* __restrict__ bsum, int nb) {
    __shared__ int sh[1024];
    int tid = threadIdx.x;
    int v = (tid < nb) ? bsum[tid] : 0;
    sh[tid] = v;
    __syncthreads();
    for (int d = 1; d < 1024; d <<= 1) {
        int t = (tid >= d) ? sh[tid - d] : 0;
        __syncthreads();
        sh[tid] += t;
        __syncthreads();
    }
    if (tid < nb) bsum[tid] = sh[tid] - v;      // exclusive block offsets
}

__global__ void scan3_k(int* __restrict__ rowptr, const int* __restrict__ bsum,
                        int* __restrict__ cursor, int nn, int ne) {
    int i = blockIdx.x * blockDim.x + threadIdx.x;
    if (i < nn) {
        int r = rowptr[i] + bsum[i >> 10];
        rowptr[i] = r;
        cursor[i] = r;
    }
    if (i == 0) rowptr[nn] = ne;
}

__global__ void fill_k(const int* __restrict__ src, const int* __restrict__ dst,
                       int* __restrict__ cursor, int* __restrict__ csr, int ne) {
    int i = blockIdx.x * blockDim.x + threadIdx.x;
    if (i < ne) {
        int p = atomicAdd(&cursor[dst[i]], 1);
        csr[p] = src[i];
    }
}

// transpose W1 (128x128) and W2 (128x64) into WT1[j][k], WT2[j][k]
__global__ void transpose_k(const float* __restrict__ W1, const float* __restrict__ W2,
                            float* __restrict__ WT1, float* __restrict__ WT2) {
    int i = blockIdx.x * blockDim.x + threadIdx.x;
    if (i < 128 * 128) {
        int k = i >> 7, j = i & 127;
        WT1[j * 128 + k] = W1[i];
    }
    int i2 = i - 128 * 128;
    if (i2 >= 0 && i2 < 128 * 64) {
        int k = i2 >> 6, j = i2 & 63;
        WT2[j * 128 + k] = W2[i2];
    }
}

// ---------------- dense transform: H[row][j] = sum_k X[row][k] * WT[j][k] ----------------
// One row per thread; x row in 32 float4 VGPRs; WT rows are wave-uniform -> scalar loads.
template <int K, int NO>
__global__ __launch_bounds__(256) void gemm_k(const float* __restrict__ X,
                                              const float* __restrict__ WT,
                                              float* __restrict__ H, int nrows) {
    int row = blockIdx.x * 256 + threadIdx.x;
    if (row >= nrows) return;
    float4 xr[K / 4];
    const float4* xp = (const float4*)(X + (size_t)row * K);
#pragma unroll
    for (int i = 0; i < K / 4; i++) xr[i] = xp[i];
    float4* op = (float4*)(H + (size_t)row * NO);
    for (int j4 = 0; j4 < NO / 4; j4++) {
        const float4* w0 = (const float4*)(WT + (size_t)(j4 * 4 + 0) * K);
        const float4* w1 = (const float4*)(WT + (size_t)(j4 * 4 + 1) * K);
        const float4* w2 = (const float4*)(WT + (size_t)(j4 * 4 + 2) * K);
        const float4* w3 = (const float4*)(WT + (size_t)(j4 * 4 + 3) * K);
        float a0 = 0.f, a1 = 0.f, a2 = 0.f, a3 = 0.f;
#pragma unroll
        for (int i = 0; i < K / 4; i++) {
            float4 v = xr[i];
            float4 b0 = w0[i]; a0 += v.x * b0.x + v.y * b0.y + v.z * b0.z + v.w * b0.w;
            float4 b1 = w1[i]; a1 += v.x * b1.x + v.y * b1.y + v.z * b1.z + v.w * b1.w;
            float4 b2 = w2[i]; a2 += v.x * b2.x + v.y * b2.y + v.z * b2.z + v.w * b2.w;
            float4 b3 = w3[i]; a3 += v.x * b3.x + v.y * b3.y + v.z * b3.z + v.w * b3.w;
        }
        float4 r; r.x = a0; r.y = a1; r.z = a2; r.w = a3;
        op[j4] = r;
    }
}

// ---------------- aggregation: out[n] = dinv[n]*(dinv[n]*h[n] + sum_src dinv[s]*h[s]) + b ----------------
// One wave per node. 4 lane-groups of 16 lanes each handle one edge per iteration
// (4 independent row gathers in flight); __shfl_xor(16/32) reduces across groups.
template <int NF, bool RELU>
__global__ __launch_bounds__(256) void agg_k(const float* __restrict__ H,
                                             const int* __restrict__ rowptr,
                                             const int* __restrict__ csr,
                                             const float* __restrict__ dinv,
                                             const float* __restrict__ bias,
                                             float* __restrict__ Out, int nn) {
    constexpr int VPL = NF / 16;   // floats per lane (8 or 4)
    constexpr int NV4 = VPL / 4;   // float4s per lane (2 or 1)
    int wid = (int)((blockIdx.x * (size_t)blockDim.x + threadIdx.x) >> 6);
    if (wid >= nn) return;
    int lane = threadIdx.x & 63;
    int g = lane >> 4, t = lane & 15;
    float dn = dinv[wid];
    float acc[VPL];
#pragma unroll
    for (int j = 0; j < VPL; j++) acc[j] = 0.f;

    int beg = rowptr[wid], end = rowptr[wid + 1];
    for (int e0 = beg; e0 < end; e0 += 4) {
        int e = e0 + g;
        int s = 0;
        float w = 0.f;
        if (e < end) {          // exec-masked: no OOB csr/dinv loads
            s = csr[e];
            w = dinv[s];
        }
        const float4* hp = (const float4*)(H + (size_t)s * NF) + t * NV4;
#pragma unroll
        for (int q = 0; q < NV4; q++) {
            float4 hv = hp[q];
            acc[q * 4 + 0] += hv.x * w;
            acc[q * 4 + 1] += hv.y * w;
            acc[q * 4 + 2] += hv.z * w;
            acc[q * 4 + 3] += hv.w * w;
        }
    }
#pragma unroll
    for (int j = 0; j < VPL; j++) {
        acc[j] += __shfl_xor(acc[j], 16);
        acc[j] += __shfl_xor(acc[j], 32);
    }
    // self-loop (all lanes compute identically; only group 0 writes)
    const float4* hn = (const float4*)(H + (size_t)wid * NF) + t * NV4;
#pragma unroll
    for (int q = 0; q < NV4; q++) {
        float4 hv = hn[q];
        acc[q * 4 + 0] += hv.x * dn;
        acc[q * 4 + 1] += hv.y * dn;
        acc[q * 4 + 2] += hv.z * dn;
        acc[q * 4 + 3] += hv.w * dn;
    }
    if (g == 0) {
        float4* op = (float4*)(Out + (size_t)wid * NF) + t * NV4;
        const float4* bp = (const float4*)bias + t * NV4;
#pragma unroll
        for (int q = 0; q < NV4; q++) {
            float4 b4 = bp[q];
            float4 r;
            r.x = acc[q * 4 + 0] * dn + b4.x;
            r.y = acc[q * 4 + 1] * dn + b4.y;
            r.z = acc[q * 4 + 2] * dn + b4.z;
            r.w = acc[q * 4 + 3] * dn + b4.w;
            if (RELU) {
                r.x = fmaxf(r.x, 0.f);
                r.y = fmaxf(r.y, 0.f);
                r.z = fmaxf(r.z, 0.f);
                r.w = fmaxf(r.w, 0.f);
            }
            op[q] = r;
        }
    }
}

// ---------------- launch ----------------

extern "C" void kernel_launch(void* const* d_in, const int* in_sizes, int n_in,
                              void* d_out, int out_size, void* d_ws, size_t ws_size,
                              hipStream_t stream) {
    const float* x  = (const float*)d_in[0];
    const int* ei   = (const int*)d_in[1];
    const float* W1 = (const float*)d_in[2];
    const float* b1 = (const float*)d_in[3];
    const float* W2 = (const float*)d_in[4];
    const float* b2 = (const float*)d_in[5];
    float* out = (float*)d_out;

    const int IN = 128, HID = 128, OUT = 64;
    int nn = in_sizes[0] / IN;     // 100000
    int ne = in_sizes[1] / 2;      // 1600000
    const int* src = ei;
    const int* dst = ei + ne;

    // workspace carve-up (256B aligned)
    char* w = (char*)d_ws;
    size_t off = 0;
    auto take = [&](size_t bytes) -> void* {
        void* p = w + off;
        off = (off + bytes + 255) & ~(size_t)255;
        return p;
    };
    int*   deg    = (int*)take((size_t)nn * 4);
    float* dinv   = (float*)take((size_t)nn * 4);
    int*   rowptr = (int*)take((size_t)(nn + 1) * 4);
    int*   cursor = (int*)take((size_t)nn * 4);
    int*   bsum   = (int*)take(1024 * 4);
    int*   csr    = (int*)take((size_t)ne * 4);
    float* WT1    = (float*)take(128 * 128 * 4);
    float* WT2    = (float*)take(64 * 128 * 4);
    float* h      = (float*)take((size_t)nn * HID * 4);
    float* h1     = (float*)take((size_t)nn * HID * 4);
    float* h2     = h;  // reuse: h dead after agg1

    (void)ws_size; (void)n_in; (void)out_size;

    hipMemsetAsync(deg, 0, (size_t)nn * 4, stream);

    int tb = 256;
    deg_count_k<<<(ne + tb - 1) / tb, tb, 0, stream>>>(dst, ne, deg);
    dinv_k<<<(nn + tb - 1) / tb, tb, 0, stream>>>(deg, dinv, nn);

    int nb = (nn + 1023) / 1024;   // 98
    scan1_k<<<nb, 1024, 0, stream>>>(deg, rowptr, bsum, nn);
    scan2_k<<<1, 1024, 0, stream>>>(bsum, nb);
    scan3_k<<<(nn + tb - 1) / tb, tb, 0, stream>>>(rowptr, bsum, cursor, nn, ne);
    fill_k<<<(ne + tb - 1) / tb, tb, 0, stream>>>(src, dst, cursor, csr, ne);

    transpose_k<<<(128 * 128 + 128 * 64 + tb - 1) / tb, tb, 0, stream>>>(W1, W2, WT1, WT2);

    // layer 1: h = x @ W1 ; h1 = relu(agg(h) + b1)
    gemm_k<128, 128><<<(nn + tb - 1) / tb, tb, 0, stream>>>(x, WT1, h, nn);
    agg_k<128, true><<<(nn * 64 + tb - 1) / tb, tb, 0, stream>>>(h, rowptr, csr, dinv, b1, h1, nn);

    // layer 2: h2 = h1 @ W2 ; out = agg(h2) + b2
    gemm_k<128, 64><<<(nn + tb - 1) / tb, tb, 0, stream>>>(h1, WT2, h2, nn);
    agg_k<64, false><<<(nn * 64 + tb - 1) / tb, tb, 0, stream>>>(h2, rowptr, csr, dinv, b2, out, nn);
}

// Round 2
// 473.566 us; speedup vs baseline: 1.8098x; 1.8098x over previous
//
#include <hip/hip_runtime.h>

// ---------------- graph prep kernels ----------------

__global__ void deg_count_k(const int* __restrict__ dst, int ne, int* __restrict__ deg) {
    int i = blockIdx.x * blockDim.x + threadIdx.x;
    if (i < ne) atomicAdd(&deg[dst[i]], 1);
}

__global__ void dinv_k(const int* __restrict__ deg, float* __restrict__ dinv, int nn) {
    int i = blockIdx.x * blockDim.x + threadIdx.x;
    if (i < nn) dinv[i] = rsqrtf((float)(deg[i] + 1));  // +1 self-loop; always > 0
}

// exclusive scan, hierarchical: scan1 (per-block) -> scan2 (block sums) -> scan3 (add offsets)
__global__ __launch_bounds__(1024) void scan1_k(const int* __restrict__ deg, int* __restrict__ exc,
                                                int* __restrict__ bsum, int nn) {
    __shared__ int sh[1024];
    int tid = threadIdx.x;
    int i = blockIdx.x * 1024 + tid;
    int v = (i < nn) ? deg[i] : 0;
    sh[tid] = v;
    __syncthreads();
    for (int d = 1; d < 1024; d <<= 1) {
        int t = (tid >= d) ? sh[tid - d] : 0;
        __syncthreads();
        sh[tid] += t;
        __syncthreads();
    }
    if (i < nn) exc[i] = sh[tid] - v;           // exclusive within block
    if (tid == 1023) bsum[blockIdx.x] = sh[1023];
}

__global__ __launch_bounds__(1024) void scan2_k(int* __restrict__ bsum, int nb) {
    __shared__ int sh[1024];
    int tid = threadIdx.x;
    int v = (tid < nb) ? bsum[tid] : 0;
    sh[tid] = v;
    __syncthreads();
    for (int d = 1; d < 1024; d <<= 1) {
        int t = (tid >= d) ? sh[tid - d] : 0;
        __syncthreads();
        sh[tid] += t;
        __syncthreads();
    }
    if (tid < nb) bsum[tid] = sh[tid] - v;      // exclusive block offsets
}

__global__ void scan3_k(int* __restrict__ rowptr, const int* __restrict__ bsum,
                        int* __restrict__ cursor, int nn, int ne) {
    int i = blockIdx.x * blockDim.x + threadIdx.x;
    if (i < nn) {
        int r = rowptr[i] + bsum[i >> 10];
        rowptr[i] = r;
        cursor[i] = r;
    }
    if (i == 0) rowptr[nn] = ne;
}

__global__ void fill_k(const int* __restrict__ src, const int* __restrict__ dst,
                       int* __restrict__ cursor, int* __restrict__ csr, int ne) {
    int i = blockIdx.x * blockDim.x + threadIdx.x;
    if (i < ne) {
        int p = atomicAdd(&cursor[dst[i]], 1);
        csr[p] = src[i];
    }
}

// ---------------- dense transform: H = X @ W  (W in original [k][j] layout) ----------------
// Block computes ROWS x NO tile with 256 threads; thread = 4 rows x 8 cols (32 acc VGPRs).
// x chunk staged TRANSPOSED in LDS (xs[k][row], padded stride) -> a-read is one ds_read_b128;
// W chunk staged as ws[k][j] -> b-read is two ds_read_b128. 32 FMAs per k per thread.
template <int NO, int ROWS>
__global__ __launch_bounds__(256) void gemm_k(const float* __restrict__ X,
                                              const float* __restrict__ W,
                                              float* __restrict__ H, int nrows) {
    constexpr int K = 128;
    constexpr int KC = 16;              // k-chunk
    constexpr int TCS = NO / 8;         // threads along cols (16 or 8)
    constexpr int XP = ROWS + 4;        // padded x stride (keeps 16B align, breaks bank stride)
    static_assert(256 / TCS * 4 == ROWS, "thread map");
    __shared__ float xs[KC][XP];
    __shared__ float ws[KC][NO];
    int t = threadIdx.x;
    int tc = t % TCS, tr = t / TCS;
    int rbase = blockIdx.x * ROWS;

    float acc[4][8];
#pragma unroll
    for (int r = 0; r < 4; r++)
#pragma unroll
        for (int j = 0; j < 8; j++) acc[r][j] = 0.f;

    for (int kc = 0; kc < K; kc += KC) {
        // stage x tile (ROWS x KC), transposed into xs[k][row]
        constexpr int XL4 = ROWS / 64;  // float4 loads per thread (1 or 2)
#pragma unroll
        for (int q = 0; q < XL4; q++) {
            int idx = t + q * 256;                  // 0 .. ROWS*4-1
            int row = idx >> 2, c = idx & 3;
            int rg = rbase + row;
            if (rg >= nrows) rg = nrows - 1;        // clamp (no OOB, tail rows unused)
            float4 v = *(const float4*)(X + (size_t)rg * K + kc + c * 4);
            xs[c * 4 + 0][row] = v.x;
            xs[c * 4 + 1][row] = v.y;
            xs[c * 4 + 2][row] = v.z;
            xs[c * 4 + 3][row] = v.w;
        }
        // stage W chunk (KC x NO), native layout
        constexpr int WL4 = NO / 64;    // float4 loads per thread (2 or 1)
#pragma unroll
        for (int q = 0; q < WL4; q++) {
            int idx = t + q * 256;                  // 0 .. KC*NO/4-1
            int k = idx / (NO / 4), c4 = idx % (NO / 4);
            *(float4*)&ws[k][c4 * 4] = *(const float4*)(W + (size_t)(kc + k) * NO + c4 * 4);
        }
        __syncthreads();
#pragma unroll
        for (int k = 0; k < KC; k++) {
            float4 a = *(const float4*)&xs[k][tr * 4];
            float4 b0 = *(const float4*)&ws[k][tc * 8];
            float4 b1 = *(const float4*)&ws[k][tc * 8 + 4];
            float av[4] = {a.x, a.y, a.z, a.w};
            float bv[8] = {b0.x, b0.y, b0.z, b0.w, b1.x, b1.y, b1.z, b1.w};
#pragma unroll
            for (int r = 0; r < 4; r++)
#pragma unroll
                for (int j = 0; j < 8; j++) acc[r][j] += av[r] * bv[j];
        }
        __syncthreads();
    }
    // epilogue
#pragma unroll
    for (int r = 0; r < 4; r++) {
        int rg = rbase + tr * 4 + r;
        if (rg < nrows) {
            float4 o0, o1;
            o0.x = acc[r][0]; o0.y = acc[r][1]; o0.z = acc[r][2]; o0.w = acc[r][3];
            o1.x = acc[r][4]; o1.y = acc[r][5]; o1.z = acc[r][6]; o1.w = acc[r][7];
            float4* op = (float4*)(H + (size_t)rg * NO + tc * 8);
            op[0] = o0;
            op[1] = o1;
        }
    }
}

// ---------------- aggregation: out[n] = dinv[n]*(dinv[n]*h[n] + sum_src dinv[s]*h[s]) + b ----------------
// One wave per node. 4 lane-groups of 16 lanes each handle one edge per iteration
// (4 independent row gathers in flight); __shfl_xor(16/32) reduces across groups.
template <int NF, bool RELU>
__global__ __launch_bounds__(256) void agg_k(const float* __restrict__ H,
                                             const int* __restrict__ rowptr,
                                             const int* __restrict__ csr,
                                             const float* __restrict__ dinv,
                                             const float* __restrict__ bias,
                                             float* __restrict__ Out, int nn) {
    constexpr int VPL = NF / 16;   // floats per lane (8 or 4)
    constexpr int NV4 = VPL / 4;   // float4s per lane (2 or 1)
    int wid = (int)((blockIdx.x * (size_t)blockDim.x + threadIdx.x) >> 6);
    if (wid >= nn) return;
    int lane = threadIdx.x & 63;
    int g = lane >> 4, t = lane & 15;
    float dn = dinv[wid];
    float acc[VPL];
#pragma unroll
    for (int j = 0; j < VPL; j++) acc[j] = 0.f;

    int beg = rowptr[wid], end = rowptr[wid + 1];
    for (int e0 = beg; e0 < end; e0 += 4) {
        int e = e0 + g;
        int s = 0;
        float w = 0.f;
        if (e < end) {          // exec-masked: no OOB csr/dinv loads
            s = csr[e];
            w = dinv[s];
        }
        const float4* hp = (const float4*)(H + (size_t)s * NF) + t * NV4;
#pragma unroll
        for (int q = 0; q < NV4; q++) {
            float4 hv = hp[q];
            acc[q * 4 + 0] += hv.x * w;
            acc[q * 4 + 1] += hv.y * w;
            acc[q * 4 + 2] += hv.z * w;
            acc[q * 4 + 3] += hv.w * w;
        }
    }
#pragma unroll
    for (int j = 0; j < VPL; j++) {
        acc[j] += __shfl_xor(acc[j], 16);
        acc[j] += __shfl_xor(acc[j], 32);
    }
    // self-loop (all lanes compute identically; only group 0 writes)
    const float4* hn = (const float4*)(H + (size_t)wid * NF) + t * NV4;
#pragma unroll
    for (int q = 0; q < NV4; q++) {
        float4 hv = hn[q];
        acc[q * 4 + 0] += hv.x * dn;
        acc[q * 4 + 1] += hv.y * dn;
        acc[q * 4 + 2] += hv.z * dn;
        acc[q * 4 + 3] += hv.w * dn;
    }
    if (g == 0) {
        float4* op = (float4*)(Out + (size_t)wid * NF) + t * NV4;
        const float4* bp = (const float4*)bias + t * NV4;
#pragma unroll
        for (int q = 0; q < NV4; q++) {
            float4 b4 = bp[q];
            float4 r;
            r.x = acc[q * 4 + 0] * dn + b4.x;
            r.y = acc[q * 4 + 1] * dn + b4.y;
            r.z = acc[q * 4 + 2] * dn + b4.z;
            r.w = acc[q * 4 + 3] * dn + b4.w;
            if (RELU) {
                r.x = fmaxf(r.x, 0.f);
                r.y = fmaxf(r.y, 0.f);
                r.z = fmaxf(r.z, 0.f);
                r.w = fmaxf(r.w, 0.f);
            }
            op[q] = r;
        }
    }
}

// ---------------- launch ----------------

extern "C" void kernel_launch(void* const* d_in, const int* in_sizes, int n_in,
                              void* d_out, int out_size, void* d_ws, size_t ws_size,
                              hipStream_t stream) {
    const float* x  = (const float*)d_in[0];
    const int* ei   = (const int*)d_in[1];
    const float* W1 = (const float*)d_in[2];
    const float* b1 = (const float*)d_in[3];
    const float* W2 = (const float*)d_in[4];
    const float* b2 = (const float*)d_in[5];
    float* out = (float*)d_out;

    const int IN = 128, HID = 128;
    int nn = in_sizes[0] / IN;     // 100000
    int ne = in_sizes[1] / 2;      // 1600000
    const int* src = ei;
    const int* dst = ei + ne;

    // workspace carve-up (256B aligned)
    char* w = (char*)d_ws;
    size_t off = 0;
    auto take = [&](size_t bytes) -> void* {
        void* p = w + off;
        off = (off + bytes + 255) & ~(size_t)255;
        return p;
    };
    int*   deg    = (int*)take((size_t)nn * 4);
    float* dinv   = (float*)take((size_t)nn * 4);
    int*   rowptr = (int*)take((size_t)(nn + 1) * 4);
    int*   cursor = (int*)take((size_t)nn * 4);
    int*   bsum   = (int*)take(1024 * 4);
    int*   csr    = (int*)take((size_t)ne * 4);
    float* h      = (float*)take((size_t)nn * HID * 4);
    float* h1     = (float*)take((size_t)nn * HID * 4);
    float* h2     = h;  // reuse: h dead after agg1

    (void)ws_size; (void)n_in; (void)out_size;

    hipMemsetAsync(deg, 0, (size_t)nn * 4, stream);

    int tb = 256;
    deg_count_k<<<(ne + tb - 1) / tb, tb, 0, stream>>>(dst, ne, deg);
    dinv_k<<<(nn + tb - 1) / tb, tb, 0, stream>>>(deg, dinv, nn);

    int nb = (nn + 1023) / 1024;   // 98
    scan1_k<<<nb, 1024, 0, stream>>>(deg, rowptr, bsum, nn);
    scan2_k<<<1, 1024, 0, stream>>>(bsum, nb);
    scan3_k<<<(nn + tb - 1) / tb, tb, 0, stream>>>(rowptr, bsum, cursor, nn, ne);
    fill_k<<<(ne + tb - 1) / tb, tb, 0, stream>>>(src, dst, cursor, csr, ne);

    // layer 1: h = x @ W1 ; h1 = relu(agg(h) + b1)
    gemm_k<128, 64><<<(nn + 63) / 64, tb, 0, stream>>>(x, W1, h, nn);
    agg_k<128, true><<<(nn * 64 + tb - 1) / tb, tb, 0, stream>>>(h, rowptr, csr, dinv, b1, h1, nn);

    // layer 2: h2 = h1 @ W2 ; out = agg(h2) + b2
    gemm_k<64, 128><<<(nn + 127) / 128, tb, 0, stream>>>(h1, W2, h2, nn);
    agg_k<64, false><<<(nn * 64 + tb - 1) / tb, tb, 0, stream>>>(h2, rowptr, csr, dinv, b2, out, nn);
}

// Round 3
// 322.164 us; speedup vs baseline: 2.6603x; 1.4700x over previous
//
#include <hip/hip_runtime.h>

// Buckets: 512 nodes each, up to 256 buckets (nn <= 131072).
#define NBK 256
#define BSHIFT 9
#define NPB 512

// ---- A1: per-bucket edge histogram ----
__global__ __launch_bounds__(256) void histA_k(const int* __restrict__ dst, int ne,
                                               int* __restrict__ gcount) {
    __shared__ int h[NBK];
    for (int i = threadIdx.x; i < NBK; i += 256) h[i] = 0;
    __syncthreads();
    int e0 = blockIdx.x * 4096;
    int e1 = min(e0 + 4096, ne);
    for (int e = e0 + (int)threadIdx.x; e < e1; e += 256)
        atomicAdd(&h[dst[e] >> BSHIFT], 1);
    __syncthreads();
    for (int i = threadIdx.x; i < NBK; i += 256)
        if (h[i]) atomicAdd(&gcount[i], h[i]);
}

// ---- A2: exclusive scan of bucket counts -> bases + cursors; sentinel rowptr[nn] ----
__global__ __launch_bounds__(256) void scanB_k(const int* __restrict__ gcount,
                                               int* __restrict__ gbase,
                                               int* __restrict__ cursor,
                                               int* __restrict__ rowptr,
                                               int nn, int ne) {
    __shared__ int sh[NBK];
    int t = threadIdx.x;
    int v = gcount[t];
    sh[t] = v;
    __syncthreads();
    for (int d = 1; d < NBK; d <<= 1) {
        int u = (t >= d) ? sh[t - d] : 0;
        __syncthreads();
        sh[t] += u;
        __syncthreads();
    }
    int ex = sh[t] - v;
    gbase[t] = ex;
    cursor[t] = ex;
    if (t == NBK - 1) gbase[NBK] = sh[t];   // == ne
    if (t == 0) rowptr[nn] = ne;
}

// ---- A3: partition edges into bucket regions, packed (dst_local<<17)|src ----
// All scatter happens in LDS; global writes are contiguous per-bucket runs.
__global__ __launch_bounds__(512) void partA_k(const int* __restrict__ src,
                                               const int* __restrict__ dst,
                                               int* __restrict__ cursor,
                                               int* __restrict__ bucketed, int ne) {
    constexpr int EPB = 8192;
    __shared__ int hist[NBK], lofs[NBK + 1], lcur[NBK], gbs[NBK], sc[NBK];
    __shared__ int stage[EPB];
    int t = threadIdx.x;
    int e0 = blockIdx.x * EPB;
    int e1 = min(e0 + EPB, ne);
    int cnt = e1 - e0;
    for (int i = t; i < NBK; i += 512) hist[i] = 0;
    __syncthreads();
    int sv[16], dv[16];
#pragma unroll
    for (int k = 0; k < 16; k++) {
        int e = e0 + t + k * 512;
        int s = 0, d = 0;
        if (e < e1) {
            s = src[e];
            d = dst[e];
            atomicAdd(&hist[d >> BSHIFT], 1);
        }
        sv[k] = s;
        dv[k] = d;
    }
    __syncthreads();
    // scan hist (first 256 threads)
    if (t < NBK) sc[t] = hist[t];
    __syncthreads();
    for (int d = 1; d < NBK; d <<= 1) {
        int u = 0;
        if (t < NBK && t >= d) u = sc[t - d];
        __syncthreads();
        if (t < NBK) sc[t] += u;
        __syncthreads();
    }
    if (t < NBK) {
        int ex = sc[t] - hist[t];
        lofs[t] = ex;
        lcur[t] = ex;
        gbs[t] = hist[t] ? atomicAdd(&cursor[t], hist[t]) : 0;
    }
    if (t == 0) lofs[NBK] = cnt;
    __syncthreads();
    // scatter into LDS, grouped by bucket
#pragma unroll
    for (int k = 0; k < 16; k++) {
        int e = e0 + t + k * 512;
        if (e < e1) {
            int b = dv[k] >> BSHIFT;
            int q = atomicAdd(&lcur[b], 1);
            stage[q] = ((dv[k] & (NPB - 1)) << 17) | sv[k];
        }
    }
    __syncthreads();
    // copy out: contiguous run per bucket (binary search bucket of idx)
    for (int idx = t; idx < cnt; idx += 512) {
        int lo = 0, hi = NBK;
        while (hi - lo > 1) {
            int mid = (lo + hi) >> 1;
            if (lofs[mid] <= idx) lo = mid; else hi = mid;
        }
        bucketed[gbs[lo] + (idx - lofs[lo])] = stage[idx];
    }
}

// ---- B: per-bucket CSR finalize + rowptr + dinv, all coalesced ----
__global__ __launch_bounds__(1024) void csrB_k(const int* __restrict__ bucketed,
                                               const int* __restrict__ gbase,
                                               int* __restrict__ csr,
                                               int* __restrict__ rowptr,
                                               float* __restrict__ dinv, int nn) {
    constexpr int CAP = 10240;
    __shared__ int cnt[NPB], ofs[NPB], cur[NPB];
    __shared__ int stage[CAP];
    int t = threadIdx.x;
    int b = blockIdx.x;
    int beg = gbase[b], end = gbase[b + 1];
    int m = end - beg;
    if (t < NPB) cnt[t] = 0;
    __syncthreads();
    for (int i = t; i < m; i += 1024)
        atomicAdd(&cnt[bucketed[beg + i] >> 17], 1);
    __syncthreads();
    int v = (t < NPB) ? cnt[t] : 0;
    if (t < NPB) ofs[t] = v;
    __syncthreads();
    for (int d = 1; d < NPB; d <<= 1) {
        int u = 0;
        if (t < NPB && t >= d) u = ofs[t - d];
        __syncthreads();
        if (t < NPB) ofs[t] += u;
        __syncthreads();
    }
    if (t < NPB) {
        int ex = ofs[t] - v;
        cur[t] = ex;
        int node = b * NPB + t;
        if (node < nn) {
            rowptr[node] = beg + ex;
            dinv[node] = rsqrtf((float)(v + 1));   // +1 self-loop
        }
    }
    __syncthreads();
    if (m <= CAP) {
        for (int i = t; i < m; i += 1024) {
            int pv = bucketed[beg + i];
            int p = atomicAdd(&cur[pv >> 17], 1);
            stage[p] = pv & 0x1FFFF;
        }
        __syncthreads();
        for (int i = t; i < m; i += 1024) csr[beg + i] = stage[i];
    } else {  // defensive fallback (never expected at this size)
        for (int i = t; i < m; i += 1024) {
            int pv = bucketed[beg + i];
            int p = atomicAdd(&cur[pv >> 17], 1);
            csr[beg + p] = pv & 0x1FFFF;
        }
    }
}

// ---------------- dense transform: H = X @ W  (W in original [k][j] layout) ----------------
template <int NO, int ROWS>
__global__ __launch_bounds__(256) void gemm_k(const float* __restrict__ X,
                                              const float* __restrict__ W,
                                              float* __restrict__ H, int nrows) {
    constexpr int K = 128;
    constexpr int KC = 16;
    constexpr int TCS = NO / 8;
    constexpr int XP = ROWS + 4;
    static_assert(256 / TCS * 4 == ROWS, "thread map");
    __shared__ float xs[KC][XP];
    __shared__ float ws[KC][NO];
    int t = threadIdx.x;
    int tc = t % TCS, tr = t / TCS;
    int rbase = blockIdx.x * ROWS;

    float acc[4][8];
#pragma unroll
    for (int r = 0; r < 4; r++)
#pragma unroll
        for (int j = 0; j < 8; j++) acc[r][j] = 0.f;

    for (int kc = 0; kc < K; kc += KC) {
        constexpr int XL4 = ROWS / 64;
#pragma unroll
        for (int q = 0; q < XL4; q++) {
            int idx = t + q * 256;
            int row = idx >> 2, c = idx & 3;
            int rg = rbase + row;
            if (rg >= nrows) rg = nrows - 1;
            float4 vx = *(const float4*)(X + (size_t)rg * K + kc + c * 4);
            xs[c * 4 + 0][row] = vx.x;
            xs[c * 4 + 1][row] = vx.y;
            xs[c * 4 + 2][row] = vx.z;
            xs[c * 4 + 3][row] = vx.w;
        }
        constexpr int WL4 = NO / 64;
#pragma unroll
        for (int q = 0; q < WL4; q++) {
            int idx = t + q * 256;
            int k = idx / (NO / 4), c4 = idx % (NO / 4);
            *(float4*)&ws[k][c4 * 4] = *(const float4*)(W + (size_t)(kc + k) * NO + c4 * 4);
        }
        __syncthreads();
#pragma unroll
        for (int k = 0; k < KC; k++) {
            float4 a = *(const float4*)&xs[k][tr * 4];
            float4 b0 = *(const float4*)&ws[k][tc * 8];
            float4 b1 = *(const float4*)&ws[k][tc * 8 + 4];
            float av[4] = {a.x, a.y, a.z, a.w};
            float bv[8] = {b0.x, b0.y, b0.z, b0.w, b1.x, b1.y, b1.z, b1.w};
#pragma unroll
            for (int r = 0; r < 4; r++)
#pragma unroll
                for (int j = 0; j < 8; j++) acc[r][j] += av[r] * bv[j];
        }
        __syncthreads();
    }
#pragma unroll
    for (int r = 0; r < 4; r++) {
        int rg = rbase + tr * 4 + r;
        if (rg < nrows) {
            float4 o0, o1;
            o0.x = acc[r][0]; o0.y = acc[r][1]; o0.z = acc[r][2]; o0.w = acc[r][3];
            o1.x = acc[r][4]; o1.y = acc[r][5]; o1.z = acc[r][6]; o1.w = acc[r][7];
            float4* op = (float4*)(H + (size_t)rg * NO + tc * 8);
            op[0] = o0;
            op[1] = o1;
        }
    }
}

// ---------------- aggregation ----------------
template <int NF, bool RELU>
__global__ __launch_bounds__(256) void agg_k(const float* __restrict__ H,
                                             const int* __restrict__ rowptr,
                                             const int* __restrict__ csr,
                                             const float* __restrict__ dinv,
                                             const float* __restrict__ bias,
                                             float* __restrict__ Out, int nn) {
    constexpr int VPL = NF / 16;
    constexpr int NV4 = VPL / 4;
    int wid = (int)((blockIdx.x * (size_t)blockDim.x + threadIdx.x) >> 6);
    if (wid >= nn) return;
    int lane = threadIdx.x & 63;
    int g = lane >> 4, t = lane & 15;
    float dn = dinv[wid];
    float acc[VPL];
#pragma unroll
    for (int j = 0; j < VPL; j++) acc[j] = 0.f;

    int beg = rowptr[wid], end = rowptr[wid + 1];
    for (int e0 = beg; e0 < end; e0 += 4) {
        int e = e0 + g;
        int s = 0;
        float w = 0.f;
        if (e < end) {
            s = csr[e];
            w = dinv[s];
        }
        const float4* hp = (const float4*)(H + (size_t)s * NF) + t * NV4;
#pragma unroll
        for (int q = 0; q < NV4; q++) {
            float4 hv = hp[q];
            acc[q * 4 + 0] += hv.x * w;
            acc[q * 4 + 1] += hv.y * w;
            acc[q * 4 + 2] += hv.z * w;
            acc[q * 4 + 3] += hv.w * w;
        }
    }
#pragma unroll
    for (int j = 0; j < VPL; j++) {
        acc[j] += __shfl_xor(acc[j], 16);
        acc[j] += __shfl_xor(acc[j], 32);
    }
    const float4* hn = (const float4*)(H + (size_t)wid * NF) + t * NV4;
#pragma unroll
    for (int q = 0; q < NV4; q++) {
        float4 hv = hn[q];
        acc[q * 4 + 0] += hv.x * dn;
        acc[q * 4 + 1] += hv.y * dn;
        acc[q * 4 + 2] += hv.z * dn;
        acc[q * 4 + 3] += hv.w * dn;
    }
    if (g == 0) {
        float4* op = (float4*)(Out + (size_t)wid * NF) + t * NV4;
        const float4* bp = (const float4*)bias + t * NV4;
#pragma unroll
        for (int q = 0; q < NV4; q++) {
            float4 b4 = bp[q];
            float4 r;
            r.x = acc[q * 4 + 0] * dn + b4.x;
            r.y = acc[q * 4 + 1] * dn + b4.y;
            r.z = acc[q * 4 + 2] * dn + b4.z;
            r.w = acc[q * 4 + 3] * dn + b4.w;
            if (RELU) {
                r.x = fmaxf(r.x, 0.f);
                r.y = fmaxf(r.y, 0.f);
                r.z = fmaxf(r.z, 0.f);
                r.w = fmaxf(r.w, 0.f);
            }
            op[q] = r;
        }
    }
}

// ---------------- launch ----------------

extern "C" void kernel_launch(void* const* d_in, const int* in_sizes, int n_in,
                              void* d_out, int out_size, void* d_ws, size_t ws_size,
                              hipStream_t stream) {
    const float* x  = (const float*)d_in[0];
    const int* ei   = (const int*)d_in[1];
    const float* W1 = (const float*)d_in[2];
    const float* b1 = (const float*)d_in[3];
    const float* W2 = (const float*)d_in[4];
    const float* b2 = (const float*)d_in[5];
    float* out = (float*)d_out;

    const int IN = 128, HID = 128;
    int nn = in_sizes[0] / IN;     // 100000
    int ne = in_sizes[1] / 2;      // 1600000
    const int* src = ei;
    const int* dst = ei + ne;
    int nbuckets = (nn + NPB - 1) / NPB;   // 196 (<= NBK)

    char* w = (char*)d_ws;
    size_t off = 0;
    auto take = [&](size_t bytes) -> void* {
        void* p = w + off;
        off = (off + bytes + 255) & ~(size_t)255;
        return p;
    };
    int*   gcount = (int*)take(NBK * 4);
    int*   gbase  = (int*)take((NBK + 1) * 4);
    int*   cursor = (int*)take(NBK * 4);
    int*   rowptr = (int*)take((size_t)(nn + 1) * 4);
    float* dinv   = (float*)take((size_t)nn * 4);
    int*   csr    = (int*)take((size_t)ne * 4);
    float* h      = (float*)take((size_t)nn * HID * 4);
    float* h1     = (float*)take((size_t)nn * HID * 4);
    float* h2     = h;                     // reuse: h dead after agg1
    int*   bucketed = (int*)h;             // reuse: dead before gemm1 writes h

    (void)ws_size; (void)n_in; (void)out_size;

    hipMemsetAsync(gcount, 0, NBK * 4, stream);

    int tb = 256;
    histA_k<<<(ne + 4095) / 4096, 256, 0, stream>>>(dst, ne, gcount);
    scanB_k<<<1, NBK, 0, stream>>>(gcount, gbase, cursor, rowptr, nn, ne);
    partA_k<<<(ne + 8191) / 8192, 512, 0, stream>>>(src, dst, cursor, bucketed, ne);
    csrB_k<<<nbuckets, 1024, 0, stream>>>(bucketed, gbase, csr, rowptr, dinv, nn);

    // layer 1: h = x @ W1 ; h1 = relu(agg(h) + b1)
    gemm_k<128, 64><<<(nn + 63) / 64, tb, 0, stream>>>(x, W1, h, nn);
    agg_k<128, true><<<(nn * 64 + tb - 1) / tb, tb, 0, stream>>>(h, rowptr, csr, dinv, b1, h1, nn);

    // layer 2: h2 = h1 @ W2 ; out = agg(h2) + b2
    gemm_k<64, 128><<<(nn + 127) / 128, tb, 0, stream>>>(h1, W2, h2, nn);
    agg_k<64, false><<<(nn * 64 + tb - 1) / tb, tb, 0, stream>>>(h2, rowptr, csr, dinv, b2, out, nn);
}

// Round 4
// 263.105 us; speedup vs baseline: 3.2574x; 1.2245x over previous
//
#include <hip/hip_runtime.h>
#include <hip/hip_fp16.h>
#include <type_traits>

// Buckets: 512 nodes each, up to 256 buckets (nn <= 131072).
#define NBK 256
#define BSHIFT 9
#define NPB 512

template <int N> struct alignas(4 * N) HVec { __half2 v[N]; };

// ---- A1: per-bucket edge histogram ----
__global__ __launch_bounds__(256) void histA_k(const int* __restrict__ dst, int ne,
                                               int* __restrict__ gcount) {
    __shared__ int h[NBK];
    for (int i = threadIdx.x; i < NBK; i += 256) h[i] = 0;
    __syncthreads();
    int e0 = blockIdx.x * 4096;
    int e1 = min(e0 + 4096, ne);
    for (int e = e0 + (int)threadIdx.x; e < e1; e += 256)
        atomicAdd(&h[dst[e] >> BSHIFT], 1);
    __syncthreads();
    for (int i = threadIdx.x; i < NBK; i += 256)
        if (h[i]) atomicAdd(&gcount[i], h[i]);
}

// ---- A2: exclusive scan of bucket counts -> bases + cursors; sentinel rowptr[nn] ----
__global__ __launch_bounds__(256) void scanB_k(const int* __restrict__ gcount,
                                               int* __restrict__ gbase,
                                               int* __restrict__ cursor,
                                               int* __restrict__ rowptr,
                                               int nn, int ne) {
    __shared__ int sh[NBK];
    int t = threadIdx.x;
    int v = gcount[t];
    sh[t] = v;
    __syncthreads();
    for (int d = 1; d < NBK; d <<= 1) {
        int u = (t >= d) ? sh[t - d] : 0;
        __syncthreads();
        sh[t] += u;
        __syncthreads();
    }
    int ex = sh[t] - v;
    gbase[t] = ex;
    cursor[t] = ex;
    if (t == NBK - 1) gbase[NBK] = sh[t];   // == ne
    if (t == 0) rowptr[nn] = ne;
}

// ---- A3: partition edges into bucket regions, packed (dst_local<<17)|src ----
__global__ __launch_bounds__(512) void partA_k(const int* __restrict__ src,
                                               const int* __restrict__ dst,
                                               int* __restrict__ cursor,
                                               int* __restrict__ bucketed, int ne) {
    constexpr int EPB = 8192;
    __shared__ int hist[NBK], lofs[NBK + 1], lcur[NBK], gbs[NBK], sc[NBK];
    __shared__ int stage[EPB];
    int t = threadIdx.x;
    int e0 = blockIdx.x * EPB;
    int e1 = min(e0 + EPB, ne);
    int cnt = e1 - e0;
    for (int i = t; i < NBK; i += 512) hist[i] = 0;
    __syncthreads();
    int sv[16], dv[16];
#pragma unroll
    for (int k = 0; k < 16; k++) {
        int e = e0 + t + k * 512;
        int s = 0, d = 0;
        if (e < e1) {
            s = src[e];
            d = dst[e];
            atomicAdd(&hist[d >> BSHIFT], 1);
        }
        sv[k] = s;
        dv[k] = d;
    }
    __syncthreads();
    if (t < NBK) sc[t] = hist[t];
    __syncthreads();
    for (int d = 1; d < NBK; d <<= 1) {
        int u = 0;
        if (t < NBK && t >= d) u = sc[t - d];
        __syncthreads();
        if (t < NBK) sc[t] += u;
        __syncthreads();
    }
    if (t < NBK) {
        int ex = sc[t] - hist[t];
        lofs[t] = ex;
        lcur[t] = ex;
        gbs[t] = hist[t] ? atomicAdd(&cursor[t], hist[t]) : 0;
    }
    if (t == 0) lofs[NBK] = cnt;
    __syncthreads();
#pragma unroll
    for (int k = 0; k < 16; k++) {
        int e = e0 + t + k * 512;
        if (e < e1) {
            int b = dv[k] >> BSHIFT;
            int q = atomicAdd(&lcur[b], 1);
            stage[q] = ((dv[k] & (NPB - 1)) << 17) | sv[k];
        }
    }
    __syncthreads();
    for (int idx = t; idx < cnt; idx += 512) {
        int lo = 0, hi = NBK;
        while (hi - lo > 1) {
            int mid = (lo + hi) >> 1;
            if (lofs[mid] <= idx) lo = mid; else hi = mid;
        }
        bucketed[gbs[lo] + (idx - lofs[lo])] = stage[idx];
    }
}

// ---- B: per-bucket CSR finalize + rowptr + dinv, all coalesced ----
__global__ __launch_bounds__(1024) void csrB_k(const int* __restrict__ bucketed,
                                               const int* __restrict__ gbase,
                                               int* __restrict__ csr,
                                               int* __restrict__ rowptr,
                                               float* __restrict__ dinv, int nn) {
    constexpr int CAP = 10240;
    __shared__ int cnt[NPB], ofs[NPB], cur[NPB];
    __shared__ int stage[CAP];
    int t = threadIdx.x;
    int b = blockIdx.x;
    int beg = gbase[b], end = gbase[b + 1];
    int m = end - beg;
    if (t < NPB) cnt[t] = 0;
    __syncthreads();
    for (int i = t; i < m; i += 1024)
        atomicAdd(&cnt[bucketed[beg + i] >> 17], 1);
    __syncthreads();
    int v = (t < NPB) ? cnt[t] : 0;
    if (t < NPB) ofs[t] = v;
    __syncthreads();
    for (int d = 1; d < NPB; d <<= 1) {
        int u = 0;
        if (t < NPB && t >= d) u = ofs[t - d];
        __syncthreads();
        if (t < NPB) ofs[t] += u;
        __syncthreads();
    }
    if (t < NPB) {
        int ex = ofs[t] - v;
        cur[t] = ex;
        int node = b * NPB + t;
        if (node < nn) {
            rowptr[node] = beg + ex;
            dinv[node] = rsqrtf((float)(v + 1));   // +1 self-loop
        }
    }
    __syncthreads();
    if (m <= CAP) {
        for (int i = t; i < m; i += 1024) {
            int pv = bucketed[beg + i];
            int p = atomicAdd(&cur[pv >> 17], 1);
            stage[p] = pv & 0x1FFFF;
        }
        __syncthreads();
        for (int i = t; i < m; i += 1024) csr[beg + i] = stage[i];
    } else {
        for (int i = t; i < m; i += 1024) {
            int pv = bucketed[beg + i];
            int p = atomicAdd(&cur[pv >> 17], 1);
            csr[beg + p] = pv & 0x1FFFF;
        }
    }
}

// ---------------- dense transform: H = X @ W, output fp16 ----------------
// XT = float (layer 1) or __half (layer 2). Accumulation fp32 in LDS/VGPRs.
template <int NO, int ROWS, typename XT>
__global__ __launch_bounds__(256) void gemm_k(const XT* __restrict__ X,
                                              const float* __restrict__ W,
                                              __half* __restrict__ H, int nrows) {
    constexpr int K = 128;
    constexpr int KC = 16;
    constexpr int TCS = NO / 8;
    constexpr int XP = ROWS + 4;
    static_assert(256 / TCS * 4 == ROWS, "thread map");
    __shared__ float xs[KC][XP];
    __shared__ float ws[KC][NO];
    int t = threadIdx.x;
    int tc = t % TCS, tr = t / TCS;
    int rbase = blockIdx.x * ROWS;

    float acc[4][8];
#pragma unroll
    for (int r = 0; r < 4; r++)
#pragma unroll
        for (int j = 0; j < 8; j++) acc[r][j] = 0.f;

    for (int kc = 0; kc < K; kc += KC) {
        if constexpr (std::is_same<XT, float>::value) {
            constexpr int XL4 = ROWS / 64;
#pragma unroll
            for (int q = 0; q < XL4; q++) {
                int idx = t + q * 256;
                int row = idx >> 2, c = idx & 3;
                int rg = rbase + row;
                if (rg >= nrows) rg = nrows - 1;
                float4 vx = *(const float4*)(X + (size_t)rg * K + kc + c * 4);
                xs[c * 4 + 0][row] = vx.x;
                xs[c * 4 + 1][row] = vx.y;
                xs[c * 4 + 2][row] = vx.z;
                xs[c * 4 + 3][row] = vx.w;
            }
        } else {
            // fp16 X: ROWS*KC halves; each thread loads 8 halves (16B)
            static_assert(ROWS * KC / 8 == 256, "fp16 stage map");
            int row = t >> 1, c = t & 1;          // c: k-offset 8*c
            int rg = rbase + row;
            if (rg >= nrows) rg = nrows - 1;
            HVec<4> hv = *(const HVec<4>*)(X + (size_t)rg * K + kc + c * 8);
#pragma unroll
            for (int j = 0; j < 4; j++) {
                float2 f = __half22float2(hv.v[j]);
                xs[c * 8 + 2 * j + 0][row] = f.x;
                xs[c * 8 + 2 * j + 1][row] = f.y;
            }
        }
        constexpr int WL4 = NO / 64;
#pragma unroll
        for (int q = 0; q < WL4; q++) {
            int idx = t + q * 256;
            int k = idx / (NO / 4), c4 = idx % (NO / 4);
            *(float4*)&ws[k][c4 * 4] = *(const float4*)(W + (size_t)(kc + k) * NO + c4 * 4);
        }
        __syncthreads();
#pragma unroll
        for (int k = 0; k < KC; k++) {
            float4 a = *(const float4*)&xs[k][tr * 4];
            float4 b0 = *(const float4*)&ws[k][tc * 8];
            float4 b1 = *(const float4*)&ws[k][tc * 8 + 4];
            float av[4] = {a.x, a.y, a.z, a.w};
            float bv[8] = {b0.x, b0.y, b0.z, b0.w, b1.x, b1.y, b1.z, b1.w};
#pragma unroll
            for (int r = 0; r < 4; r++)
#pragma unroll
                for (int j = 0; j < 8; j++) acc[r][j] += av[r] * bv[j];
        }
        __syncthreads();
    }
#pragma unroll
    for (int r = 0; r < 4; r++) {
        int rg = rbase + tr * 4 + r;
        if (rg < nrows) {
            HVec<4> o;
#pragma unroll
            for (int q = 0; q < 4; q++)
                o.v[q] = __floats2half2_rn(acc[r][2 * q], acc[r][2 * q + 1]);
            *(HVec<4>*)(H + (size_t)rg * NO + tc * 8) = o;
        }
    }
}

// ---------------- aggregation: fp16 gather, fp32 accumulate ----------------
// One wave per node; 4 lane-groups of 16; edge loop unrolled 2x (8 edges in flight).
template <int NF, bool RELU, typename OutT>
__global__ __launch_bounds__(256) void agg_k(const __half* __restrict__ H,
                                             const int* __restrict__ rowptr,
                                             const int* __restrict__ csr,
                                             const float* __restrict__ dinv,
                                             const float* __restrict__ bias,
                                             OutT* __restrict__ Out, int nn) {
    constexpr int VPL = NF / 16;        // values per lane (8 or 4)
    constexpr int NV2 = VPL / 2;        // half2 per lane (4 or 2)
    int wid = (int)((blockIdx.x * (size_t)blockDim.x + threadIdx.x) >> 6);
    if (wid >= nn) return;
    int lane = threadIdx.x & 63;
    int g = lane >> 4, t = lane & 15;
    float dn = dinv[wid];
    float acc[VPL];
#pragma unroll
    for (int j = 0; j < VPL; j++) acc[j] = 0.f;

    int beg = rowptr[wid], end = rowptr[wid + 1];
    for (int e0 = beg; e0 < end; e0 += 8) {
        int eA = e0 + g, eB = e0 + g + 4;
        int sA = 0, sB = 0;
        float wA = 0.f, wB = 0.f;
        if (eA < end) { sA = csr[eA]; wA = dinv[sA]; }
        if (eB < end) { sB = csr[eB]; wB = dinv[sB]; }
        HVec<NV2> a = *((const HVec<NV2>*)(H + (size_t)sA * NF) + t);
        HVec<NV2> b = *((const HVec<NV2>*)(H + (size_t)sB * NF) + t);
#pragma unroll
        for (int q = 0; q < NV2; q++) {
            float2 fa = __half22float2(a.v[q]);
            float2 fb = __half22float2(b.v[q]);
            acc[2 * q + 0] += fa.x * wA + fb.x * wB;
            acc[2 * q + 1] += fa.y * wA + fb.y * wB;
        }
    }
#pragma unroll
    for (int j = 0; j < VPL; j++) {
        acc[j] += __shfl_xor(acc[j], 16);
        acc[j] += __shfl_xor(acc[j], 32);
    }
    // self-loop
    HVec<NV2> hn = *((const HVec<NV2>*)(H + (size_t)wid * NF) + t);
#pragma unroll
    for (int q = 0; q < NV2; q++) {
        float2 f = __half22float2(hn.v[q]);
        acc[2 * q + 0] += f.x * dn;
        acc[2 * q + 1] += f.y * dn;
    }
    if (g == 0) {
        float r[VPL];
#pragma unroll
        for (int j = 0; j < VPL; j++) {
            r[j] = acc[j] * dn + bias[t * VPL + j];
            if (RELU) r[j] = fmaxf(r[j], 0.f);
        }
        if constexpr (std::is_same<OutT, __half>::value) {
            HVec<NV2> o;
#pragma unroll
            for (int q = 0; q < NV2; q++)
                o.v[q] = __floats2half2_rn(r[2 * q], r[2 * q + 1]);
            *((HVec<NV2>*)(Out + (size_t)wid * NF) + t) = o;
        } else {
#pragma unroll
            for (int q = 0; q < VPL / 4; q++) {
                float4 o;
                o.x = r[4 * q + 0]; o.y = r[4 * q + 1];
                o.z = r[4 * q + 2]; o.w = r[4 * q + 3];
                *((float4*)(Out + (size_t)wid * NF) + t * (VPL / 4) + q) = o;
            }
        }
    }
}

// ---------------- launch ----------------

extern "C" void kernel_launch(void* const* d_in, const int* in_sizes, int n_in,
                              void* d_out, int out_size, void* d_ws, size_t ws_size,
                              hipStream_t stream) {
    const float* x  = (const float*)d_in[0];
    const int* ei   = (const int*)d_in[1];
    const float* W1 = (const float*)d_in[2];
    const float* b1 = (const float*)d_in[3];
    const float* W2 = (const float*)d_in[4];
    const float* b2 = (const float*)d_in[5];
    float* out = (float*)d_out;

    const int IN = 128, HID = 128;
    int nn = in_sizes[0] / IN;     // 100000
    int ne = in_sizes[1] / 2;      // 1600000
    const int* src = ei;
    const int* dst = ei + ne;
    int nbuckets = (nn + NPB - 1) / NPB;   // 196 (<= NBK)

    char* w = (char*)d_ws;
    size_t off = 0;
    auto take = [&](size_t bytes) -> void* {
        void* p = w + off;
        off = (off + bytes + 255) & ~(size_t)255;
        return p;
    };
    int*    gcount = (int*)take(NBK * 4);
    int*    gbase  = (int*)take((NBK + 1) * 4);
    int*    cursor = (int*)take(NBK * 4);
    int*    rowptr = (int*)take((size_t)(nn + 1) * 4);
    float*  dinv   = (float*)take((size_t)nn * 4);
    int*    csr    = (int*)take((size_t)ne * 4);
    __half* h      = (__half*)take((size_t)nn * HID * 2);
    __half* h1     = (__half*)take((size_t)nn * HID * 2);
    __half* h2     = h;                    // reuse: h dead after agg1
    int*    bucketed = (int*)h;            // reuse: dead before gemm1 writes h

    (void)ws_size; (void)n_in; (void)out_size;

    hipMemsetAsync(gcount, 0, NBK * 4, stream);

    int tb = 256;
    histA_k<<<(ne + 4095) / 4096, 256, 0, stream>>>(dst, ne, gcount);
    scanB_k<<<1, NBK, 0, stream>>>(gcount, gbase, cursor, rowptr, nn, ne);
    partA_k<<<(ne + 8191) / 8192, 512, 0, stream>>>(src, dst, cursor, bucketed, ne);
    csrB_k<<<nbuckets, 1024, 0, stream>>>(bucketed, gbase, csr, rowptr, dinv, nn);

    // layer 1: h = x @ W1 ; h1 = relu(agg(h) + b1)
    gemm_k<128, 64, float><<<(nn + 63) / 64, tb, 0, stream>>>(x, W1, h, nn);
    agg_k<128, true, __half><<<(nn * 64 + tb - 1) / tb, tb, 0, stream>>>(h, rowptr, csr, dinv, b1, h1, nn);

    // layer 2: h2 = h1 @ W2 ; out = agg(h2) + b2
    gemm_k<64, 128, __half><<<(nn + 127) / 128, tb, 0, stream>>>(h1, W2, h2, nn);
    agg_k<64, false, float><<<(nn * 64 + tb - 1) / tb, tb, 0, stream>>>(h2, rowptr, csr, dinv, b2, out, nn);
}

// Round 5
// 224.614 us; speedup vs baseline: 3.8156x; 1.1714x over previous
//
#include <hip/hip_runtime.h>
#include <hip/hip_fp16.h>
#include <type_traits>

// Buckets: 512 nodes each, up to 256 buckets (nn <= 131072).
#define NBK 256
#define BSHIFT 9
#define NPB 512

template <int N> struct alignas(4 * N) HVec { __half2 v[N]; };

typedef _Float16 half8 __attribute__((ext_vector_type(8)));
typedef float f32x4 __attribute__((ext_vector_type(4)));

// ---- A1: per-bucket edge histogram ----
__global__ __launch_bounds__(256) void histA_k(const int* __restrict__ dst, int ne,
                                               int* __restrict__ gcount) {
    __shared__ int h[NBK];
    for (int i = threadIdx.x; i < NBK; i += 256) h[i] = 0;
    __syncthreads();
    int e0 = blockIdx.x * 4096;
    int e1 = min(e0 + 4096, ne);
    for (int e = e0 + (int)threadIdx.x; e < e1; e += 256)
        atomicAdd(&h[dst[e] >> BSHIFT], 1);
    __syncthreads();
    for (int i = threadIdx.x; i < NBK; i += 256)
        if (h[i]) atomicAdd(&gcount[i], h[i]);
}

// ---- A2: exclusive scan of bucket counts -> bases + cursors; sentinel rowptr[nn] ----
__global__ __launch_bounds__(256) void scanB_k(const int* __restrict__ gcount,
                                               int* __restrict__ gbase,
                                               int* __restrict__ cursor,
                                               int* __restrict__ rowptr,
                                               int nn, int ne) {
    __shared__ int sh[NBK];
    int t = threadIdx.x;
    int v = gcount[t];
    sh[t] = v;
    __syncthreads();
    for (int d = 1; d < NBK; d <<= 1) {
        int u = (t >= d) ? sh[t - d] : 0;
        __syncthreads();
        sh[t] += u;
        __syncthreads();
    }
    int ex = sh[t] - v;
    gbase[t] = ex;
    cursor[t] = ex;
    if (t == NBK - 1) gbase[NBK] = sh[t];   // == ne
    if (t == 0) rowptr[nn] = ne;
}

// ---- A3: partition edges into bucket regions, packed (dst_local<<17)|src ----
__global__ __launch_bounds__(512) void partA_k(const int* __restrict__ src,
                                               const int* __restrict__ dst,
                                               int* __restrict__ cursor,
                                               int* __restrict__ bucketed, int ne) {
    constexpr int EPB = 8192;
    __shared__ int hist[NBK], lofs[NBK + 1], lcur[NBK], gbs[NBK], sc[NBK];
    __shared__ int stage[EPB];
    int t = threadIdx.x;
    int e0 = blockIdx.x * EPB;
    int e1 = min(e0 + EPB, ne);
    int cnt = e1 - e0;
    for (int i = t; i < NBK; i += 512) hist[i] = 0;
    __syncthreads();
    int sv[16], dv[16];
#pragma unroll
    for (int k = 0; k < 16; k++) {
        int e = e0 + t + k * 512;
        int s = 0, d = 0;
        if (e < e1) {
            s = src[e];
            d = dst[e];
            atomicAdd(&hist[d >> BSHIFT], 1);
        }
        sv[k] = s;
        dv[k] = d;
    }
    __syncthreads();
    if (t < NBK) sc[t] = hist[t];
    __syncthreads();
    for (int d = 1; d < NBK; d <<= 1) {
        int u = 0;
        if (t < NBK && t >= d) u = sc[t - d];
        __syncthreads();
        if (t < NBK) sc[t] += u;
        __syncthreads();
    }
    if (t < NBK) {
        int ex = sc[t] - hist[t];
        lofs[t] = ex;
        lcur[t] = ex;
        gbs[t] = hist[t] ? atomicAdd(&cursor[t], hist[t]) : 0;
    }
    if (t == 0) lofs[NBK] = cnt;
    __syncthreads();
#pragma unroll
    for (int k = 0; k < 16; k++) {
        int e = e0 + t + k * 512;
        if (e < e1) {
            int b = dv[k] >> BSHIFT;
            int q = atomicAdd(&lcur[b], 1);
            stage[q] = ((dv[k] & (NPB - 1)) << 17) | sv[k];
        }
    }
    __syncthreads();
    for (int idx = t; idx < cnt; idx += 512) {
        int lo = 0, hi = NBK;
        while (hi - lo > 1) {
            int mid = (lo + hi) >> 1;
            if (lofs[mid] <= idx) lo = mid; else hi = mid;
        }
        bucketed[gbs[lo] + (idx - lofs[lo])] = stage[idx];
    }
}

// ---- B: per-bucket CSR finalize + rowptr + dinv, all coalesced ----
__global__ __launch_bounds__(1024) void csrB_k(const int* __restrict__ bucketed,
                                               const int* __restrict__ gbase,
                                               int* __restrict__ csr,
                                               int* __restrict__ rowptr,
                                               float* __restrict__ dinv, int nn) {
    constexpr int CAP = 10240;
    __shared__ int cnt[NPB], ofs[NPB], cur[NPB];
    __shared__ int stage[CAP];
    int t = threadIdx.x;
    int b = blockIdx.x;
    int beg = gbase[b], end = gbase[b + 1];
    int m = end - beg;
    if (t < NPB) cnt[t] = 0;
    __syncthreads();
    for (int i = t; i < m; i += 1024)
        atomicAdd(&cnt[bucketed[beg + i] >> 17], 1);
    __syncthreads();
    int v = (t < NPB) ? cnt[t] : 0;
    if (t < NPB) ofs[t] = v;
    __syncthreads();
    for (int d = 1; d < NPB; d <<= 1) {
        int u = 0;
        if (t < NPB && t >= d) u = ofs[t - d];
        __syncthreads();
        if (t < NPB) ofs[t] += u;
        __syncthreads();
    }
    if (t < NPB) {
        int ex = ofs[t] - v;
        cur[t] = ex;
        int node = b * NPB + t;
        if (node < nn) {
            rowptr[node] = beg + ex;
            dinv[node] = rsqrtf((float)(v + 1));   // +1 self-loop
        }
    }
    __syncthreads();
    if (m <= CAP) {
        for (int i = t; i < m; i += 1024) {
            int pv = bucketed[beg + i];
            int p = atomicAdd(&cur[pv >> 17], 1);
            stage[p] = pv & 0x1FFFF;
        }
        __syncthreads();
        for (int i = t; i < m; i += 1024) csr[beg + i] = stage[i];
    } else {
        for (int i = t; i < m; i += 1024) {
            int pv = bucketed[beg + i];
            int p = atomicAdd(&cur[pv >> 17], 1);
            csr[beg + p] = pv & 0x1FFFF;
        }
    }
}

// ---- W prep: transpose + fp16 cast. WT1[j][k] (128x128), WT2[j][k] (64x128) ----
__global__ void prepW_k(const float* __restrict__ W1, const float* __restrict__ W2,
                        _Float16* __restrict__ WT1, _Float16* __restrict__ WT2) {
    int i = blockIdx.x * blockDim.x + threadIdx.x;
    if (i < 128 * 128) {
        int k = i >> 7, j = i & 127;
        WT1[j * 128 + k] = (_Float16)W1[i];
    }
    int i2 = i - 128 * 128;
    if (i2 >= 0 && i2 < 128 * 64) {
        int k = i2 >> 6, j = i2 & 63;
        WT2[j * 128 + k] = (_Float16)W2[i2];
    }
}

// ---------------- MFMA dense transform: H = X @ W (fp16 in, fp32 acc, fp16 out) ----------------
// One wave per 16-row tile. A-frag: row=lane&15, k=(lane>>4)*8+j (k-contiguous 16B).
// B-frag from WT[col][k]: col=lane&15, k-contiguous 16B (L1-resident, 32KB shared).
// D: col=lane&15, row=(lane>>4)*4+reg. SCALE multiplies rows by dinv (h' = dinv .* XW).
template <int NO, bool SCALE, typename XT>
__global__ __launch_bounds__(256) void gemm_mfma_k(const XT* __restrict__ X,
                                                   const _Float16* __restrict__ WT,
                                                   const float* __restrict__ dinv,
                                                   _Float16* __restrict__ H, int nrows) {
    constexpr int K = 128;
    constexpr int NCT = NO / 16;
    int wv = (int)((blockIdx.x * (size_t)blockDim.x + threadIdx.x) >> 6);
    int r0 = wv * 16;
    if (r0 >= nrows) return;
    int lane = threadIdx.x & 63;
    int lr = lane & 15;          // A-row / D-col
    int kg = lane >> 4;          // k-group
    int rg = r0 + lr;
    if (rg >= nrows) rg = nrows - 1;   // clamp (stores are guarded)

    half8 a[4];
    if constexpr (std::is_same<XT, float>::value) {
#pragma unroll
        for (int ks = 0; ks < 4; ks++) {
            const float* px = X + (size_t)rg * K + ks * 32 + kg * 8;
            float4 x0 = *(const float4*)px;
            float4 x1 = *(const float4*)(px + 4);
            half8 vv;
            vv[0] = (_Float16)x0.x; vv[1] = (_Float16)x0.y;
            vv[2] = (_Float16)x0.z; vv[3] = (_Float16)x0.w;
            vv[4] = (_Float16)x1.x; vv[5] = (_Float16)x1.y;
            vv[6] = (_Float16)x1.z; vv[7] = (_Float16)x1.w;
            a[ks] = vv;
        }
    } else {
#pragma unroll
        for (int ks = 0; ks < 4; ks++)
            a[ks] = *(const half8*)(X + (size_t)rg * K + ks * 32 + kg * 8);
    }

    f32x4 acc[NCT];
#pragma unroll
    for (int ct = 0; ct < NCT; ct++) acc[ct] = (f32x4){0.f, 0.f, 0.f, 0.f};
#pragma unroll
    for (int ct = 0; ct < NCT; ct++) {
#pragma unroll
        for (int ks = 0; ks < 4; ks++) {
            half8 b = *(const half8*)(WT + (size_t)(ct * 16 + lr) * K + ks * 32 + kg * 8);
            acc[ct] = __builtin_amdgcn_mfma_f32_16x16x32_f16(a[ks], b, acc[ct], 0, 0, 0);
        }
    }
    // epilogue: lane's 4 values per ct are rows kg*4+i, col lr
#pragma unroll
    for (int i = 0; i < 4; i++) {
        int rr = r0 + kg * 4 + i;
        if (rr < nrows) {
            float s = SCALE ? dinv[rr] : 1.f;
            _Float16* hp = H + (size_t)rr * NO + lr;
#pragma unroll
            for (int ct = 0; ct < NCT; ct++)
                hp[ct * 16] = (_Float16)(acc[ct][i] * s);
        }
    }
}

// ---------------- aggregation: out[n] = dinv[n]*(sum h'[s] + h'[n]) + b ----------------
// h' rows are pre-scaled by dinv, so edges are pure unweighted sums (no per-edge dinv).
// One wave per node; 4 lane-groups of 16; main loop 16 edges/iter with one fp16
// pair-add level; masked tail 4 edges/iter.
template <int NF, bool RELU, bool OUTSCALE, typename OutT>
__global__ __launch_bounds__(256) void agg_k(const __half* __restrict__ H,
                                             const int* __restrict__ rowptr,
                                             const int* __restrict__ csr,
                                             const float* __restrict__ dinv,
                                             const float* __restrict__ bias,
                                             OutT* __restrict__ Out, int nn) {
    constexpr int VPL = NF / 16;        // values per lane (8 or 4)
    constexpr int NV2 = VPL / 2;        // half2 per lane (4 or 2)
    int wid = (int)((blockIdx.x * (size_t)blockDim.x + threadIdx.x) >> 6);
    if (wid >= nn) return;
    int lane = threadIdx.x & 63;
    int g = lane >> 4, t = lane & 15;
    float acc[VPL];
#pragma unroll
    for (int j = 0; j < VPL; j++) acc[j] = 0.f;

    int beg = rowptr[wid], end = rowptr[wid + 1];
    int e0 = beg;
    // main: 16 edges per iteration (4 per group), all valid
    for (; e0 + 16 <= end; e0 += 16) {
        int eb = e0 + g * 4;
        int s0 = csr[eb + 0], s1 = csr[eb + 1], s2 = csr[eb + 2], s3 = csr[eb + 3];
        HVec<NV2> va = *((const HVec<NV2>*)(H + (size_t)s0 * NF) + t);
        HVec<NV2> vb = *((const HVec<NV2>*)(H + (size_t)s1 * NF) + t);
        HVec<NV2> vc = *((const HVec<NV2>*)(H + (size_t)s2 * NF) + t);
        HVec<NV2> vd = *((const HVec<NV2>*)(H + (size_t)s3 * NF) + t);
#pragma unroll
        for (int q = 0; q < NV2; q++) {
            __half2 pab = __hadd2(va.v[q], vb.v[q]);
            __half2 pcd = __hadd2(vc.v[q], vd.v[q]);
            float2 fab = __half22float2(pab);
            float2 fcd = __half22float2(pcd);
            acc[2 * q + 0] += fab.x + fcd.x;
            acc[2 * q + 1] += fab.y + fcd.y;
        }
    }
    // tail: up to 15 edges, masked via weight
    for (; e0 < end; e0 += 4) {
        int e = e0 + g;
        int s = 0;
        float w = 0.f;
        if (e < end) { s = csr[e]; w = 1.f; }
        HVec<NV2> va = *((const HVec<NV2>*)(H + (size_t)s * NF) + t);
#pragma unroll
        for (int q = 0; q < NV2; q++) {
            float2 f = __half22float2(va.v[q]);
            acc[2 * q + 0] += f.x * w;
            acc[2 * q + 1] += f.y * w;
        }
    }
#pragma unroll
    for (int j = 0; j < VPL; j++) {
        acc[j] += __shfl_xor(acc[j], 16);
        acc[j] += __shfl_xor(acc[j], 32);
    }
    // self-loop (h'[n], already scaled)
    HVec<NV2> hn = *((const HVec<NV2>*)(H + (size_t)wid * NF) + t);
#pragma unroll
    for (int q = 0; q < NV2; q++) {
        float2 f = __half22float2(hn.v[q]);
        acc[2 * q + 0] += f.x;
        acc[2 * q + 1] += f.y;
    }
    if (g == 0) {
        float dn = dinv[wid];
        float r[VPL];
#pragma unroll
        for (int j = 0; j < VPL; j++) {
            r[j] = acc[j] * dn + bias[t * VPL + j];
            if (RELU) r[j] = fmaxf(r[j], 0.f);
            if (OUTSCALE) r[j] *= dn;      // pre-scale for next layer's aggregation
        }
        if constexpr (std::is_same<OutT, __half>::value) {
            HVec<NV2> o;
#pragma unroll
            for (int q = 0; q < NV2; q++)
                o.v[q] = __floats2half2_rn(r[2 * q], r[2 * q + 1]);
            *((HVec<NV2>*)(Out + (size_t)wid * NF) + t) = o;
        } else {
#pragma unroll
            for (int q = 0; q < VPL / 4; q++) {
                float4 o;
                o.x = r[4 * q + 0]; o.y = r[4 * q + 1];
                o.z = r[4 * q + 2]; o.w = r[4 * q + 3];
                *((float4*)(Out + (size_t)wid * NF) + t * (VPL / 4) + q) = o;
            }
        }
    }
}

// ---------------- launch ----------------

extern "C" void kernel_launch(void* const* d_in, const int* in_sizes, int n_in,
                              void* d_out, int out_size, void* d_ws, size_t ws_size,
                              hipStream_t stream) {
    const float* x  = (const float*)d_in[0];
    const int* ei   = (const int*)d_in[1];
    const float* W1 = (const float*)d_in[2];
    const float* b1 = (const float*)d_in[3];
    const float* W2 = (const float*)d_in[4];
    const float* b2 = (const float*)d_in[5];
    float* out = (float*)d_out;

    const int IN = 128, HID = 128;
    int nn = in_sizes[0] / IN;     // 100000
    int ne = in_sizes[1] / 2;      // 1600000
    const int* src = ei;
    const int* dst = ei + ne;
    int nbuckets = (nn + NPB - 1) / NPB;   // 196 (<= NBK)

    char* w = (char*)d_ws;
    size_t off = 0;
    auto take = [&](size_t bytes) -> void* {
        void* p = w + off;
        off = (off + bytes + 255) & ~(size_t)255;
        return p;
    };
    int*      gcount = (int*)take(NBK * 4);
    int*      gbase  = (int*)take((NBK + 1) * 4);
    int*      cursor = (int*)take(NBK * 4);
    int*      rowptr = (int*)take((size_t)(nn + 1) * 4);
    float*    dinv   = (float*)take((size_t)nn * 4);
    int*      csr    = (int*)take((size_t)ne * 4);
    _Float16* WT1    = (_Float16*)take(128 * 128 * 2);
    _Float16* WT2    = (_Float16*)take(64 * 128 * 2);
    __half*   h      = (__half*)take((size_t)nn * HID * 2);
    __half*   h1     = (__half*)take((size_t)nn * HID * 2);
    __half*   h2     = h;                  // reuse: h dead after agg1
    int*      bucketed = (int*)h;          // reuse: dead before gemm1 writes h

    (void)ws_size; (void)n_in; (void)out_size;

    hipMemsetAsync(gcount, 0, NBK * 4, stream);

    int tb = 256;
    histA_k<<<(ne + 4095) / 4096, 256, 0, stream>>>(dst, ne, gcount);
    scanB_k<<<1, NBK, 0, stream>>>(gcount, gbase, cursor, rowptr, nn, ne);
    partA_k<<<(ne + 8191) / 8192, 512, 0, stream>>>(src, dst, cursor, bucketed, ne);
    csrB_k<<<nbuckets, 1024, 0, stream>>>(bucketed, gbase, csr, rowptr, dinv, nn);
    prepW_k<<<(128 * 128 + 128 * 64 + tb - 1) / tb, tb, 0, stream>>>(W1, W2, WT1, WT2);

    int gblocks = ((nn + 15) / 16 + 3) / 4;   // 1 wave per 16 rows, 4 waves/block

    // layer 1: h' = dinv .* (x @ W1)  [fp16] ; h1s = dinv .* relu(agg(h') + b1)
    gemm_mfma_k<128, true, float><<<gblocks, tb, 0, stream>>>(x, WT1, dinv, (_Float16*)h, nn);
    agg_k<128, true, true, __half><<<(nn * 64 + tb - 1) / tb, tb, 0, stream>>>(h, rowptr, csr, dinv, b1, h1, nn);

    // layer 2: h2' = h1s @ W2 (already dinv-scaled) ; out = agg(h2') + b2  [fp32]
    gemm_mfma_k<64, false, __half><<<gblocks, tb, 0, stream>>>(h1, WT2, dinv, (_Float16*)h2, nn);
    agg_k<64, false, false, float><<<(nn * 64 + tb - 1) / tb, tb, 0, stream>>>(h2, rowptr, csr, dinv, b2, out, nn);
}